// Round 3
// baseline (868.719 us; speedup 1.0000x reference)
//
#include <hip/hip_runtime.h>
#include <hip/hip_bf16.h>

// Problem: B=8192 rows, D=4096. 3 layers of relu(l2norm(h) @ W^T + b).
// GEMM: 256x256 tile, BK=64, 8 waves, 128 KiB LDS double-buffer, 4 phases
// per K-tile, counted vmcnt(4), raw s_barrier, setprio around MFMA.
// ROUND 3 change: aF fragment reads software-pipelined ONE PHASE AHEAD,
// issued after the lgkmcnt(0) gate so they flow down the LDS pipe while the
// matrix pipe runs the current 16-MFMA cluster (LDS/MFMA were measured
// additive: 2480 cyc MFMA + 2500 cyc LDS+sync per tile -> MfmaUtil 45%).
// aF double-buffered (sets alternate per phase, static indices); bF single
// set read in ph0's window (VGPR budget: 128 acc + 32 bF + 32 aF <= 256).
// End-of-tile vmcnt(4) moved BEFORE ph3's barrier so ph3's MFMA window can
// prefetch next-tile aF[0..1] from published A(t+1).

#define NROWS 8192
#define DIM   4096

typedef __bf16 bf16x8 __attribute__((ext_vector_type(8)));
typedef float  f32x4  __attribute__((ext_vector_type(4)));

__device__ static inline short f2bf(float f) {
  __hip_bfloat16 h = __float2bfloat16(f);
  return __builtin_bit_cast(short, h);
}

// raw barrier: compiler fence + s_barrier, NO vmcnt/lgkmcnt drain
#define BARRIER() do { asm volatile("" ::: "memory"); \
                       __builtin_amdgcn_s_barrier();  \
                       asm volatile("" ::: "memory"); } while (0)
#define LGKM0()  asm volatile("s_waitcnt lgkmcnt(0)" ::: "memory")

// ---------------------------------------------------------------------------
// C[M,N] = relu(A[M,K](bf16) . Bw[N,K](bf16)^T + bias[N]), fp32 out.
// 8 waves in 2(M)x4(N); per-wave out 128x64 = acc[8][4] 16x16 frags.
//
// Steady-state tile t (buf = t&1):
//  ph0: stage A(t+1).h0; read bF[0..3] (8 b128, window); BAR; lgkm0;
//       issue aS1<-At[2..3]; MFMA(acc[0..1], aS0); BAR
//  ph1: stage A(t+1).h1; BAR; lgkm0; issue aS0<-At[4..5];
//       MFMA(acc[2..3], aS1); BAR
//  ph2: stage B(t+2).h0; BAR; lgkm0; issue aS1<-At[6..7];
//       MFMA(acc[4..5], aS0); BAR
//  ph3: stage B(t+2).h1; vmcnt(4) [A(t+1),B(t+1) land]; BAR (publish);
//       lgkm0; issue aS0<-A(t+1)[0..1]; MFMA(acc[6..7], aS1); BAR
// vmcnt ledger: entering t: B(t+1)x4 in flight; tile issues A(t+1)x4,
// B(t+2)x4 -> 12; vmcnt(4) retires B(t+1),A(t+1). Tail t>=NT-2: vmcnt(0).
// WAR: every region's readers pass lgkm0 + >=1 barrier before its re-stager
// issues (checked per phase). RAW: reads of staged data only after the
// stagers' vmcnt + barrier (ph3's wait, or prologue's).
// ---------------------------------------------------------------------------
__global__ __launch_bounds__(512, 2)
void gemm256_bias_relu(const short* __restrict__ A,
                       const short* __restrict__ Bw,
                       const float* __restrict__ bias,
                       float* __restrict__ C,
                       int M, int N, int K)
{
  __shared__ short lds[4][16384];   // [buf*2+op][256 rows * 64 bf16] = 128 KiB

  // XCD-aware swizzle (bijective: grid % 8 == 0 here)
  int bid = blockIdx.x;
  const int nwg = gridDim.x;
  if ((nwg & 7) == 0) { const int cpx = nwg >> 3; bid = (bid & 7) * cpx + (bid >> 3); }
  const int nbn  = N >> 8;
  const int brow = (bid / nbn) << 8;
  const int bcol = (bid % nbn) << 8;

  const int lane = threadIdx.x & 63;
  const int wid  = threadIdx.x >> 6;   // 0..7
  const int wr   = wid >> 2;           // 0..1 : 128-row output band
  const int wc   = wid & 3;            // 0..3 : 64-col output band

  float bv[4];
#pragma unroll
  for (int j = 0; j < 4; ++j)
    bv[j] = bias[bcol + wc * 64 + j * 16 + (lane & 15)];

  f32x4 acc[8][4] = {};

  const size_t Kz   = (size_t)K;
  const size_t rowK = Kz * 2;          // bytes per global row
  const char*  Ag   = (const char*)A;
  const char*  Bg   = (const char*)Bw;
  char* const  ldsB = (char*)&lds[0][0];

  // ---- staging addressing (coalesced, source pre-swizzled) ----
  const int r8  = lane >> 3;
  const int kcs = (lane & 7) ^ r8;
  const size_t gAl = (size_t)(brow + r8) * rowK + (size_t)kcs * 16;
  const size_t gBl = (size_t)(bcol + r8) * rowK + (size_t)kcs * 16;

  auto stage_half = [&](int tile, int op, int h) {
    const char*  gp = op ? Bg : Ag;
    const size_t gt = (op ? gBl : gAl) + (size_t)tile * 128;
    char* lb = ldsB + ((tile & 1) * 2 + op) * 32768;
#pragma unroll
    for (int s = 0; s < 2; ++s) {
      const int rb = h * 128 + s * 64 + wid * 8;
      __builtin_amdgcn_global_load_lds(
          (const __attribute__((address_space(1))) void*)(gp + gt + (size_t)rb * rowK),
          (__attribute__((address_space(3))) void*)(lb + rb * 128), 16, 0, 0);
    }
  };

  // ---- fragment read addressing (swizzled: phys kc = kc ^ (row&7)) ----
  const int l15  = lane & 15;
  const int xlo  = ((lane >> 4) ^ (lane & 3)) * 16;
  const int b2   = (lane >> 2) & 1;
  const int k64[2] = { b2 << 6, (1 - b2) << 6 };
  const int abase = (wr * 128 + l15) * 128 + xlo;
  const int bbase = (wc * 64  + l15) * 128 + xlo;

  const int NT = K >> 6;

  bf16x8 aS[2][2][2];   // [set][ii][ks] -- sets alternate per phase
  bf16x8 bF[4][2];

#define LOAD_A(SET, I0, PTR)                                                 \
  _Pragma("unroll")                                                          \
  for (int ii = 0; ii < 2; ++ii)                                             \
    _Pragma("unroll")                                                        \
    for (int ks = 0; ks < 2; ++ks)                                           \
      aS[SET][ii][ks] = *reinterpret_cast<const bf16x8*>(                    \
          (PTR) + abase + ((I0) + ii) * 2048 + k64[ks]);

#define MFMA2(I0, SET)                                                       \
  _Pragma("unroll")                                                          \
  for (int ii = 0; ii < 2; ++ii)                                             \
    _Pragma("unroll")                                                        \
    for (int j = 0; j < 4; ++j)                                              \
      _Pragma("unroll")                                                      \
      for (int ks = 0; ks < 2; ++ks)                                         \
        acc[(I0) + ii][j] = __builtin_amdgcn_mfma_f32_16x16x32_bf16(         \
            aS[SET][ii][ks], bF[j][ks], acc[(I0) + ii][j], 0, 0, 0);

  // ---- prologue: A0, B0, B1 (12 loads); land A0,B0; publish; pre-read aS0
  stage_half(0, 0, 0); stage_half(0, 0, 1);
  stage_half(0, 1, 0); stage_half(0, 1, 1);
  if (NT > 1) { stage_half(1, 1, 0); stage_half(1, 1, 1); }
  if (NT > 1) asm volatile("s_waitcnt vmcnt(4)" ::: "memory");
  else        asm volatile("s_waitcnt vmcnt(0)" ::: "memory");
  BARRIER();
  {
    const char* A0 = ldsB;
    LOAD_A(0, 0, A0)
  }

  for (int t = 0; t < NT; ++t) {
    const char* At = ldsB + ((t & 1) * 2 + 0) * 32768;
    const char* Bt = ldsB + ((t & 1) * 2 + 1) * 32768;
    const char* An = ldsB + (((t + 1) & 1) * 2 + 0) * 32768;

    // ---- phase 0: bF window read; stage A(t+1).h0 ----
    if (t + 1 < NT) stage_half(t + 1, 0, 0);
#pragma unroll
    for (int j = 0; j < 4; ++j)
#pragma unroll
      for (int ks = 0; ks < 2; ++ks)
        bF[j][ks] = *reinterpret_cast<const bf16x8*>(Bt + bbase + j * 2048 + k64[ks]);
    BARRIER();
    LGKM0();                       // bF + aS0 (prefetched in prev ph3) ready
    LOAD_A(1, 2, At)               // overlaps MFMA below
    __builtin_amdgcn_s_setprio(1);
    MFMA2(0, 0)
    __builtin_amdgcn_s_setprio(0);
    BARRIER();

    // ---- phase 1 ----
    if (t + 1 < NT) stage_half(t + 1, 0, 1);
    BARRIER();
    LGKM0();
    LOAD_A(0, 4, At)
    __builtin_amdgcn_s_setprio(1);
    MFMA2(2, 1)
    __builtin_amdgcn_s_setprio(0);
    BARRIER();

    // ---- phase 2 ----
    if (t + 2 < NT) stage_half(t + 2, 1, 0);
    BARRIER();
    LGKM0();
    LOAD_A(1, 6, At)
    __builtin_amdgcn_s_setprio(1);
    MFMA2(4, 0)
    __builtin_amdgcn_s_setprio(0);
    BARRIER();

    // ---- phase 3: counted vmcnt BEFORE barrier (publish A(t+1),B(t+1));
    //      MFMA window prefetches next tile's aS0 ----
    if (t + 2 < NT) stage_half(t + 2, 1, 1);
    if (t >= NT - 2) asm volatile("s_waitcnt vmcnt(0)" ::: "memory");
    else             asm volatile("s_waitcnt vmcnt(4)" ::: "memory");
    BARRIER();
    LGKM0();
    if (t + 1 < NT) { LOAD_A(0, 0, An) }
    __builtin_amdgcn_s_setprio(1);
    MFMA2(6, 1)
    __builtin_amdgcn_s_setprio(0);
    BARRIER();
  }
#undef MFMA2
#undef LOAD_A

  // epilogue: C/D layout col = lane&15, row = (lane>>4)*4 + reg
#pragma unroll
  for (int i = 0; i < 8; ++i) {
    const int rbase = brow + wr * 128 + i * 16 + ((lane >> 4) << 2);
#pragma unroll
    for (int j = 0; j < 4; ++j) {
      const int col = bcol + wc * 64 + j * 16 + (lane & 15);
#pragma unroll
      for (int r = 0; r < 4; ++r) {
        const float v = acc[i][j][r] + bv[j];
        C[(size_t)(rbase + r) * N + col] = v > 0.f ? v : 0.f;
      }
    }
  }
}

// ---------------------------------------------------------------------------
// Row L2-normalize (fp32 in) -> bf16 out. One block (256 thr) per row of 4096.
// ---------------------------------------------------------------------------
__global__ __launch_bounds__(256)
void rownorm_bf16(const float* __restrict__ in, short* __restrict__ out)
{
  const int row = blockIdx.x;
  const int t0  = threadIdx.x;
  const float4* inr = (const float4*)(in + (size_t)row * DIM);

  float4 v[4];
  float ss = 0.f;
#pragma unroll
  for (int t = 0; t < 4; ++t) {
    v[t] = inr[t0 + t * 256];
    ss += v[t].x * v[t].x + v[t].y * v[t].y + v[t].z * v[t].z + v[t].w * v[t].w;
  }
#pragma unroll
  for (int off = 32; off > 0; off >>= 1)
    ss += __shfl_down(ss, off, 64);

  __shared__ float wss[4];
  if ((t0 & 63) == 0) wss[t0 >> 6] = ss;
  __syncthreads();
  const float tot   = wss[0] + wss[1] + wss[2] + wss[3];
  const float scale = 1.f / fmaxf(sqrtf(tot), 1e-12f);  // F.normalize eps

  short4* outr = (short4*)(out + (size_t)row * DIM);
#pragma unroll
  for (int t = 0; t < 4; ++t) {
    short4 o;
    o.x = f2bf(v[t].x * scale);
    o.y = f2bf(v[t].y * scale);
    o.z = f2bf(v[t].z * scale);
    o.w = f2bf(v[t].w * scale);
    outr[t0 + t * 256] = o;
  }
}

// ---------------------------------------------------------------------------
// fp32 -> bf16 bulk cast (for W), vectorized, grid-stride.
// ---------------------------------------------------------------------------
__global__ __launch_bounds__(256)
void cast_bf16(const float* __restrict__ in, short* __restrict__ out, int n4)
{
  int i = blockIdx.x * 256 + threadIdx.x;
  const int stride = gridDim.x * 256;
  for (; i < n4; i += stride) {
    const float4 v = ((const float4*)in)[i];
    short4 o;
    o.x = f2bf(v.x);
    o.y = f2bf(v.y);
    o.z = f2bf(v.z);
    o.w = f2bf(v.w);
    ((short4*)out)[i] = o;
  }
}

extern "C" void kernel_launch(void* const* d_in, const int* in_sizes, int n_in,
                              void* d_out, int out_size, void* d_ws, size_t ws_size,
                              hipStream_t stream) {
  const float* x = (const float*)d_in[0];
  const float* W[3]    = { (const float*)d_in[1], (const float*)d_in[3], (const float*)d_in[5] };
  const float* bias[3] = { (const float*)d_in[2], (const float*)d_in[4], (const float*)d_in[6] };
  float* out = (float*)d_out;

  // workspace layout: hn bf16 [8192][4096] (64 MiB) | Wb bf16 [4096][4096] (32 MiB)
  short* hn = (short*)d_ws;
  short* Wb = (short*)((char*)d_ws + (size_t)NROWS * DIM * 2);

  const size_t layer_elems = (size_t)NROWS * DIM;
  const float* hin = x;

  for (int L = 0; L < 3; ++L) {
    cast_bf16<<<2048, 256, 0, stream>>>(W[L], Wb, DIM * DIM / 4);
    rownorm_bf16<<<NROWS, 256, 0, stream>>>(hin, hn);
    gemm256_bias_relu<<<(NROWS / 256) * (DIM / 256), 512, 0, stream>>>(
        hn, Wb, bias[L], out + (size_t)L * layer_elems, NROWS, DIM, DIM);
    hin = out + (size_t)L * layer_elems;
  }
}

// Round 4
// 797.889 us; speedup vs baseline: 1.0888x; 1.0888x over previous
//
#include <hip/hip_runtime.h>
#include <hip/hip_bf16.h>

// Problem: B=8192 rows, D=4096. 3 layers of relu(l2norm(h) @ W^T + b).
// GEMM: 256x256 tile, BK=64, 8 waves, 128 KiB LDS double-buffer.
// ROUND 4: (1) ONE barrier per phase (was 2) -- WAR safety re-derived:
//   pre-barrier reads of phase p are safe vs stages at phase >= p+2,
//   window reads vs >= p+3 (BAR(q-1) passage implies all waves executed
//   LGKM0(q-2)); the one violating pair (ph2-window aF[6..7] vs next-tile
//   ph0 A-stage) fixed by moving that read to ph2's PRE-barrier slot.
// (2) ks-OUTER MFMA order (no back-to-back same-acc dependent pairs).
// (3) staging row offsets rbo[] precomputed (no per-load 64-bit mul).

#define NROWS 8192
#define DIM   4096

typedef __bf16 bf16x8 __attribute__((ext_vector_type(8)));
typedef float  f32x4  __attribute__((ext_vector_type(4)));

__device__ static inline short f2bf(float f) {
  __hip_bfloat16 h = __float2bfloat16(f);
  return __builtin_bit_cast(short, h);
}

// raw barrier: compiler fence + s_barrier, NO vmcnt/lgkmcnt drain
#define BARRIER() do { asm volatile("" ::: "memory"); \
                       __builtin_amdgcn_s_barrier();  \
                       asm volatile("" ::: "memory"); } while (0)
#define LGKM0()  asm volatile("s_waitcnt lgkmcnt(0)" ::: "memory")

// ---------------------------------------------------------------------------
// C[M,N] = relu(A[M,K](bf16) . Bw[N,K](bf16)^T + bias[N]), fp32 out.
// 8 waves in 2(M)x4(N); per-wave out 128x64 = acc[8][4] 16x16 frags.
//
// Steady-state tile t (buf = t&1), ONE barrier per phase:
//  ph0: stage A(t+1).h0 | bF[0..3]<-Bt (8 rd) | BAR | lgkm0 |
//       issue aS1<-At[2..3] | MFMA(acc[0..1], aS0)
//  ph1: stage A(t+1).h1 | BAR | lgkm0 | issue aS0<-At[4..5] |
//       MFMA(acc[2..3], aS1)
//  ph2: stage B(t+2).h0 | pre-read aS1<-At[6..7] | BAR | lgkm0 |
//       MFMA(acc[4..5], aS0)
//  ph3: stage B(t+2).h1 | vmcnt(4) | BAR | lgkm0 |
//       issue aS0<-A(t+1)[0..1] | MFMA(acc[6..7], aS1)
// vmcnt ledger (per-thread): enter t with [B(t+1)x4]; +A(t+1)x4 (ph0,ph1),
// +B(t+2)x4 (ph2,ph3) -> 12; vmcnt(4) retires B(t+1),A(t+1); exit [B(t+2)x4].
// Tail t>=NT-2: vmcnt(0). RAW: readers of staged data sit after the stager's
// vmcnt + a barrier (all waves' vmcnt precedes BAR(ph3)). WAR: per the
// p+2 / p+3 rules above -- all pairs verified.
// ---------------------------------------------------------------------------
__global__ __launch_bounds__(512, 2)
void gemm256_bias_relu(const short* __restrict__ A,
                       const short* __restrict__ Bw,
                       const float* __restrict__ bias,
                       float* __restrict__ C,
                       int M, int N, int K)
{
  __shared__ short lds[4][16384];   // [buf*2+op][256 rows * 64 bf16] = 128 KiB

  // XCD-aware swizzle (bijective: grid % 8 == 0 here)
  int bid = blockIdx.x;
  const int nwg = gridDim.x;
  if ((nwg & 7) == 0) { const int cpx = nwg >> 3; bid = (bid & 7) * cpx + (bid >> 3); }
  const int nbn  = N >> 8;
  const int brow = (bid / nbn) << 8;
  const int bcol = (bid % nbn) << 8;

  const int lane = threadIdx.x & 63;
  const int wid  = threadIdx.x >> 6;   // 0..7
  const int wr   = wid >> 2;           // 0..1 : 128-row output band
  const int wc   = wid & 3;            // 0..3 : 64-col output band

  float bv[4];
#pragma unroll
  for (int j = 0; j < 4; ++j)
    bv[j] = bias[bcol + wc * 64 + j * 16 + (lane & 15)];

  f32x4 acc[8][4] = {};

  const size_t Kz   = (size_t)K;
  const size_t rowK = Kz * 2;          // bytes per global row
  char* const  ldsB = (char*)&lds[0][0];

  // ---- staging addressing (coalesced, source pre-swizzled, hoisted) ----
  const int r8  = lane >> 3;
  const int kcs = (lane & 7) ^ r8;
  const char* AgL = (const char*)A  + (size_t)(brow + r8) * rowK + (size_t)kcs * 16;
  const char* BgL = (const char*)Bw + (size_t)(bcol + r8) * rowK + (size_t)kcs * 16;
  size_t rbo[4];                       // (wid*8 + {0,64,128,192}) * rowK
  int    rbb[4];                       // same, in LDS bytes (row*128)
#pragma unroll
  for (int i = 0; i < 4; ++i) {
    const int rb = wid * 8 + i * 64;
    rbo[i] = (size_t)rb * rowK;
    rbb[i] = rb * 128;
  }

  // stage one 128-row half: 2 x global_load_lds(16B) per thread
  auto stage_half = [&](int parity, int op, int h, int tile) {
    const char* gp = (op ? BgL : AgL) + ((size_t)tile << 7);
    char* lb = ldsB + (parity * 2 + op) * 32768;
#pragma unroll
    for (int s = 0; s < 2; ++s) {
      const int idx = h * 2 + s;
      __builtin_amdgcn_global_load_lds(
          (const __attribute__((address_space(1))) void*)(gp + rbo[idx]),
          (__attribute__((address_space(3))) void*)(lb + rbb[idx]), 16, 0, 0);
    }
  };

  // ---- fragment read addressing (swizzled: phys kc = kc ^ (row&7)) ----
  const int l15  = lane & 15;
  const int xlo  = ((lane >> 4) ^ (lane & 3)) * 16;
  const int b2   = (lane >> 2) & 1;
  const int k64[2] = { b2 << 6, (1 - b2) << 6 };
  const int abase = (wr * 128 + l15) * 128 + xlo;
  const int bbase = (wc * 64  + l15) * 128 + xlo;

  const int NT = K >> 6;

  bf16x8 aS[2][2][2];   // [set][ii][ks] -- sets alternate per phase
  bf16x8 bF[4][2];

#define LOAD_A(SET, I0, PTR)                                                 \
  _Pragma("unroll")                                                          \
  for (int ii = 0; ii < 2; ++ii)                                             \
    _Pragma("unroll")                                                        \
    for (int ks = 0; ks < 2; ++ks)                                           \
      aS[SET][ii][ks] = *reinterpret_cast<const bf16x8*>(                    \
          (PTR) + abase + ((I0) + ii) * 2048 + k64[ks]);

// ks OUTERMOST: consecutive MFMAs revisit the same acc only every 8 instrs
#define MFMA2(I0, SET)                                                       \
  _Pragma("unroll")                                                          \
  for (int ks = 0; ks < 2; ++ks)                                             \
    _Pragma("unroll")                                                        \
    for (int ii = 0; ii < 2; ++ii)                                           \
      _Pragma("unroll")                                                      \
      for (int j = 0; j < 4; ++j)                                            \
        acc[(I0) + ii][j] = __builtin_amdgcn_mfma_f32_16x16x32_bf16(         \
            aS[SET][ii][ks], bF[j][ks], acc[(I0) + ii][j], 0, 0, 0);

  // ---- prologue: A0, B0, B1 (12 loads); land A0,B0; publish; pre-read aS0
  stage_half(0, 0, 0, 0); stage_half(0, 0, 1, 0);
  stage_half(0, 1, 0, 0); stage_half(0, 1, 1, 0);
  if (NT > 1) { stage_half(1, 1, 0, 1); stage_half(1, 1, 1, 1); }
  if (NT > 1) asm volatile("s_waitcnt vmcnt(4)" ::: "memory");
  else        asm volatile("s_waitcnt vmcnt(0)" ::: "memory");
  BARRIER();
  {
    const char* A0 = ldsB;
    LOAD_A(0, 0, A0)
  }

  for (int t = 0; t < NT; ++t) {
    const int cur = t & 1, nxt = cur ^ 1;
    const char* At = ldsB + (cur * 2 + 0) * 32768;
    const char* Bt = ldsB + (cur * 2 + 1) * 32768;
    const char* An = ldsB + (nxt * 2 + 0) * 32768;

    // ---- phase 0 ----
    if (t + 1 < NT) stage_half(nxt, 0, 0, t + 1);
#pragma unroll
    for (int j = 0; j < 4; ++j)
#pragma unroll
      for (int ks = 0; ks < 2; ++ks)
        bF[j][ks] = *reinterpret_cast<const bf16x8*>(Bt + bbase + j * 2048 + k64[ks]);
    BARRIER();
    LGKM0();
    LOAD_A(1, 2, At)
    __builtin_amdgcn_s_setprio(1);
    MFMA2(0, 0)
    __builtin_amdgcn_s_setprio(0);

    // ---- phase 1 ----
    if (t + 1 < NT) stage_half(nxt, 0, 1, t + 1);
    BARRIER();
    LGKM0();
    LOAD_A(0, 4, At)
    __builtin_amdgcn_s_setprio(1);
    MFMA2(2, 1)
    __builtin_amdgcn_s_setprio(0);

    // ---- phase 2 (aS1 pre-read: completes at this phase's lgkm0, which
    //      makes it safe vs next-tile ph0's A-stage) ----
    if (t + 2 < NT) stage_half(cur, 1, 0, t + 2);
    LOAD_A(1, 6, At)
    BARRIER();
    LGKM0();
    __builtin_amdgcn_s_setprio(1);
    MFMA2(4, 0)
    __builtin_amdgcn_s_setprio(0);

    // ---- phase 3: counted vmcnt before barrier (publish A(t+1),B(t+1));
    //      window prefetches next tile's aS0 ----
    if (t + 2 < NT) stage_half(cur, 1, 1, t + 2);
    if (t >= NT - 2) asm volatile("s_waitcnt vmcnt(0)" ::: "memory");
    else             asm volatile("s_waitcnt vmcnt(4)" ::: "memory");
    BARRIER();
    LGKM0();
    if (t + 1 < NT) { LOAD_A(0, 0, An) }
    __builtin_amdgcn_s_setprio(1);
    MFMA2(6, 1)
    __builtin_amdgcn_s_setprio(0);
  }
#undef MFMA2
#undef LOAD_A

  // epilogue: C/D layout col = lane&15, row = (lane>>4)*4 + reg
#pragma unroll
  for (int i = 0; i < 8; ++i) {
    const int rbase = brow + wr * 128 + i * 16 + ((lane >> 4) << 2);
#pragma unroll
    for (int j = 0; j < 4; ++j) {
      const int col = bcol + wc * 64 + j * 16 + (lane & 15);
#pragma unroll
      for (int r = 0; r < 4; ++r) {
        const float v = acc[i][j][r] + bv[j];
        C[(size_t)(rbase + r) * N + col] = v > 0.f ? v : 0.f;
      }
    }
  }
}

// ---------------------------------------------------------------------------
// Row L2-normalize (fp32 in) -> bf16 out. One block (256 thr) per row of 4096.
// ---------------------------------------------------------------------------
__global__ __launch_bounds__(256)
void rownorm_bf16(const float* __restrict__ in, short* __restrict__ out)
{
  const int row = blockIdx.x;
  const int t0  = threadIdx.x;
  const float4* inr = (const float4*)(in + (size_t)row * DIM);

  float4 v[4];
  float ss = 0.f;
#pragma unroll
  for (int t = 0; t < 4; ++t) {
    v[t] = inr[t0 + t * 256];
    ss += v[t].x * v[t].x + v[t].y * v[t].y + v[t].z * v[t].z + v[t].w * v[t].w;
  }
#pragma unroll
  for (int off = 32; off > 0; off >>= 1)
    ss += __shfl_down(ss, off, 64);

  __shared__ float wss[4];
  if ((t0 & 63) == 0) wss[t0 >> 6] = ss;
  __syncthreads();
  const float tot   = wss[0] + wss[1] + wss[2] + wss[3];
  const float scale = 1.f / fmaxf(sqrtf(tot), 1e-12f);  // F.normalize eps

  short4* outr = (short4*)(out + (size_t)row * DIM);
#pragma unroll
  for (int t = 0; t < 4; ++t) {
    short4 o;
    o.x = f2bf(v[t].x * scale);
    o.y = f2bf(v[t].y * scale);
    o.z = f2bf(v[t].z * scale);
    o.w = f2bf(v[t].w * scale);
    outr[t0 + t * 256] = o;
  }
}

// ---------------------------------------------------------------------------
// fp32 -> bf16 bulk cast (for W), vectorized, grid-stride.
// ---------------------------------------------------------------------------
__global__ __launch_bounds__(256)
void cast_bf16(const float* __restrict__ in, short* __restrict__ out, int n4)
{
  int i = blockIdx.x * 256 + threadIdx.x;
  const int stride = gridDim.x * 256;
  for (; i < n4; i += stride) {
    const float4 v = ((const float4*)in)[i];
    short4 o;
    o.x = f2bf(v.x);
    o.y = f2bf(v.y);
    o.z = f2bf(v.z);
    o.w = f2bf(v.w);
    ((short4*)out)[i] = o;
  }
}

extern "C" void kernel_launch(void* const* d_in, const int* in_sizes, int n_in,
                              void* d_out, int out_size, void* d_ws, size_t ws_size,
                              hipStream_t stream) {
  const float* x = (const float*)d_in[0];
  const float* W[3]    = { (const float*)d_in[1], (const float*)d_in[3], (const float*)d_in[5] };
  const float* bias[3] = { (const float*)d_in[2], (const float*)d_in[4], (const float*)d_in[6] };
  float* out = (float*)d_out;

  // workspace layout: hn bf16 [8192][4096] (64 MiB) | Wb bf16 [4096][4096] (32 MiB)
  short* hn = (short*)d_ws;
  short* Wb = (short*)((char*)d_ws + (size_t)NROWS * DIM * 2);

  const size_t layer_elems = (size_t)NROWS * DIM;
  const float* hin = x;

  for (int L = 0; L < 3; ++L) {
    cast_bf16<<<2048, 256, 0, stream>>>(W[L], Wb, DIM * DIM / 4);
    rownorm_bf16<<<NROWS, 256, 0, stream>>>(hin, hn);
    gemm256_bias_relu<<<(NROWS / 256) * (DIM / 256), 512, 0, stream>>>(
        hn, Wb, bias[L], out + (size_t)L * layer_elems, NROWS, DIM, DIM);
    hin = out + (size_t)L * layer_elems;
  }
}